// Round 5
// baseline (228.110 us; speedup 1.0000x reference)
//
#include <hip/hip_runtime.h>
#include <math.h>

// Problem constants (B, C, H, W) = (8, 512, 32, 32)
#define B_    8
#define C_    512
#define HW_   1024
#define O3_   1536     // 3*C
#define HEADS_ 8
#define D_    64       // head dim
#define G_    32       // groups
#define CPG_  16       // channels per group
#define EPS_  1e-5f
#define M_TOT 8192     // B*HW

// softmax scale (1/sqrt(64)) folded with log2(e) so exp2 is exact softmax
#define QSCALE (0.125f * 1.44269504088896f)

typedef __bf16 bf16x8 __attribute__((ext_vector_type(8)));
typedef __bf16 bf16x4 __attribute__((ext_vector_type(4)));
typedef float  f32x4  __attribute__((ext_vector_type(4)));

// async global->LDS, 16B per lane (wave-uniform base + lane*16 layout)
__device__ __forceinline__ void async_copy16(void* lds, const void* g) {
  __builtin_amdgcn_global_load_lds(
      (const __attribute__((address_space(1))) unsigned int*)g,
      (__attribute__((address_space(3))) unsigned int*)lds, 16, 0, 0);
}

// ---------------------------------------------------------------------------
// Kernel 1: GroupNorm -> bf16 transposed to h[b][hw][c]. (R2 version)
// ---------------------------------------------------------------------------
__global__ __launch_bounds__(1024) void k_gn(const float* __restrict__ x,
                                             const float* __restrict__ gw,
                                             const float* __restrict__ gb,
                                             __bf16* __restrict__ h,
                                             const float* __restrict__ qw,
                                             const float* __restrict__ pw,
                                             __bf16* __restrict__ qwb,
                                             __bf16* __restrict__ pwb) {
  __shared__ float red[34];
  __shared__ __bf16 T[16 * 1032];          // transpose staging (pad: 8B rows)
  int tid = threadIdx.x;
  if (blockIdx.x >= B_ * G_) {             // conversion blocks, grid-stride x4
    int i0 = (blockIdx.x - B_ * G_) * 1024 + tid;
    for (int i = i0; i < O3_ * C_ / 4; i += 64 * 1024) {
      float4 v = ((const float4*)qw)[i];
      bf16x4 o = {(__bf16)v.x, (__bf16)v.y, (__bf16)v.z, (__bf16)v.w};
      ((bf16x4*)qwb)[i] = o;
    }
    for (int i = i0; i < C_ * C_ / 4; i += 64 * 1024) {
      float4 v = ((const float4*)pw)[i];
      bf16x4 o = {(__bf16)v.x, (__bf16)v.y, (__bf16)v.z, (__bf16)v.w};
      ((bf16x4*)pwb)[i] = o;
    }
    return;
  }
  int bg = blockIdx.x;
  int b = bg >> 5, g = bg & 31;
  const float4* xg4 = (const float4*)(x + ((size_t)(b * C_) + g * CPG_) * HW_);

  // pass 1: float4 loads, sum + sumsq (slab stays L2-hot for pass 2)
  float s = 0.f, ss = 0.f;
  for (int i = tid; i < CPG_ * HW_ / 4; i += 1024) {
    float4 v = xg4[i];
    s += v.x + v.y + v.z + v.w;
    ss += v.x * v.x + v.y * v.y + v.z * v.z + v.w * v.w;
  }
  for (int off = 32; off > 0; off >>= 1) {
    s  += __shfl_down(s, off, 64);
    ss += __shfl_down(ss, off, 64);
  }
  int wv = tid >> 6;
  if ((tid & 63) == 0) { red[wv] = s; red[16 + wv] = ss; }
  __syncthreads();
  if (tid == 0) {
    float S = 0.f, SS = 0.f;
#pragma unroll
    for (int i = 0; i < 16; i++) { S += red[i]; SS += red[16 + i]; }
    float mean = S / (float)(CPG_ * HW_);
    float var  = SS / (float)(CPG_ * HW_) - mean * mean;
    red[32] = mean;
    red[33] = rsqrtf(var + EPS_);
  }
  __syncthreads();
  float mean = red[32], rstd = red[33];

  // pass 2: re-read slab (L2-hot), normalize, packed bf16x4 writes into T
  for (int i = tid; i < CPG_ * HW_ / 4; i += 1024) {
    int c = i >> 8;
    int hw4 = (i & 255) * 4;
    float ga = gw[g * CPG_ + c], be = gb[g * CPG_ + c];
    float4 v = xg4[i];
    bf16x4 pk;
    pk[0] = (__bf16)((v.x - mean) * rstd * ga + be);
    pk[1] = (__bf16)((v.y - mean) * rstd * ga + be);
    pk[2] = (__bf16)((v.z - mean) * rstd * ga + be);
    pk[3] = (__bf16)((v.w - mean) * rstd * ga + be);
    *(bf16x4*)(&T[c * 1032 + hw4]) = pk;
  }
  __syncthreads();

  // pass 3: gather 8 channels per thread, packed 16B global stores
  __bf16* hb = h + (size_t)b * HW_ * C_ + g * CPG_;
  for (int j = tid; j < 2 * HW_; j += 1024) {
    int hw = j >> 1, c8 = (j & 1) * 8;
    bf16x8 v;
#pragma unroll
    for (int jj = 0; jj < 8; jj++) v[jj] = T[(c8 + jj) * 1032 + hw];
    *(bf16x8*)(hb + (size_t)hw * C_ + c8) = v;
  }
}

// ---------------------------------------------------------------------------
// Kernel 3: QKV GEMM — R2 best (BK=32, 128x128 tile, 3 blocks/CU, depth-2
// prefetch with counted vmcnt(4)).
// ---------------------------------------------------------------------------
#define BKQ 32
__global__ __launch_bounds__(256, 3) void k_qkv(const __bf16* __restrict__ h,
                                                const __bf16* __restrict__ w,
                                                const float* __restrict__ bias,
                                                __bf16* __restrict__ y,
                                                __bf16* __restrict__ vT) {
  __shared__ __align__(16) __bf16 As[2][128 * BKQ];
  __shared__ __align__(16) __bf16 Bs[2][128 * BKQ];
  int m0 = blockIdx.x * 128, n0 = blockIdx.y * 128;
  int t = threadIdx.x;
  int lane = t & 63, l16 = lane & 15, quad = lane >> 4;
  int wv = t >> 6;
  int wm = (wv >> 1) * 64, wn = (wv & 1) * 64;

  int rsub = lane >> 2;                     // row (0..15) within the 16-row copy
  int chunk = (lane & 3) ^ (rsub & 3);      // XOR chunk swizzle (4 chunks/row)
  const __bf16* ag = h + (size_t)(m0 + wv * 32 + rsub) * C_ + chunk * 8;
  const __bf16* bg = w + (size_t)(n0 + wv * 32 + rsub) * C_ + chunk * 8;
  int sw = l16 & 3;                         // read-side row&3

  auto stage = [&](int k0, int bi) {        // exactly 4 VMEM ops per call
    __bf16* la = As[bi] + wv * 1024 + lane * 8;
    __bf16* lb = Bs[bi] + wv * 1024 + lane * 8;
#pragma unroll
    for (int s = 0; s < 2; s++) {
      async_copy16(la + s * 512, ag + (size_t)(s * 16) * C_ + k0);
      async_copy16(lb + s * 512, bg + (size_t)(s * 16) * C_ + k0);
    }
  };

  f32x4 acc[4][4];
#pragma unroll
  for (int i = 0; i < 4; i++)
#pragma unroll
    for (int j = 0; j < 4; j++) acc[i][j] = f32x4{0.f, 0.f, 0.f, 0.f};

  stage(0, 0);
  stage(1 * BKQ, 1);
  for (int kk = 0; kk < 16; kk++) {
    int bi = kk & 1;
    // wait only the oldest 4 loads (buffer bi); 4 newer stay in flight
    if (kk < 15)
      asm volatile("s_waitcnt vmcnt(4)\n\ts_barrier" ::: "memory");
    else
      asm volatile("s_waitcnt vmcnt(0)\n\ts_barrier" ::: "memory");
    const __bf16* as = As[bi];
    const __bf16* bs = Bs[bi];
    bf16x8 af[4], bf[4];
#pragma unroll
    for (int i = 0; i < 4; i++) {
      af[i] = *(const bf16x8*)(as + (wm + i * 16 + l16) * BKQ + (quad ^ sw) * 8);
      bf[i] = *(const bf16x8*)(bs + (wn + i * 16 + l16) * BKQ + (quad ^ sw) * 8);
    }
    // all waves done reading bi -> safe to overwrite it with k+2 tile
    asm volatile("s_waitcnt lgkmcnt(0)\n\ts_barrier" ::: "memory");
    if (kk < 14) stage((kk + 2) * BKQ, bi);
    __builtin_amdgcn_s_setprio(1);
#pragma unroll
    for (int i = 0; i < 4; i++)
#pragma unroll
      for (int j = 0; j < 4; j++)
        acc[i][j] = __builtin_amdgcn_mfma_f32_16x16x32_bf16(af[i], bf[j],
                                                            acc[i][j], 0, 0, 0);
    __builtin_amdgcn_s_setprio(0);
  }

  if (n0 >= 2 * C_) {
    // V region -> vT[b][c][tok]; tok = m, c = n - 1024. b uniform per block.
    int bb = m0 >> 10;
    int tokBase = (m0 & 1023) + wm + quad * 4;
#pragma unroll
    for (int j = 0; j < 4; j++) {
      int n = n0 + wn + j * 16 + l16;
      int c = n - 2 * C_;
      float bv = bias[n];
      __bf16* vrow = vT + ((size_t)(bb * C_) + c) * HW_;
#pragma unroll
      for (int i = 0; i < 4; i++) {
        bf16x4 pk;
#pragma unroll
        for (int r = 0; r < 4; r++) pk[r] = (__bf16)(acc[i][j][r] + bv);
        *(bf16x4*)(vrow + tokBase + i * 16) = pk;
      }
    }
  } else {
    float sc = (n0 < C_) ? QSCALE : 1.0f;  // block-uniform (region edges %128)
#pragma unroll
    for (int j = 0; j < 4; j++) {
      int n = n0 + wn + j * 16 + l16;
      float bv = bias[n];
#pragma unroll
      for (int i = 0; i < 4; i++)
#pragma unroll
        for (int r = 0; r < 4; r++) {
          int m = m0 + wm + i * 16 + quad * 4 + r;
          y[(size_t)m * O3_ + n] = (__bf16)((acc[i][j][r] + bv) * sc);
        }
    }
  }
}

// ---------------------------------------------------------------------------
// Kernel 4: flash attention, NO K/V LDS STAGING. K/V are L2-resident
// (256KB per (b,hd); same-hd blocks share an XCD since linear id%8 = hd) so
// fragments are loaded straight from global into MFMA register layout.
// Zero barriers (P staging LDS is per-wave), LDS 4.6KB, 16 q-rows/wave,
// grid 8x8x16 = 1024 blocks = 4 blocks/CU, ~4 waves/SIMD. 2-deep K prefetch
// with even/odd register sets (static indexing); V issued one phase early
// so its L2 latency hides under QK+exp+pack.
// ---------------------------------------------------------------------------
__global__ __launch_bounds__(256) void k_attn(const __bf16* __restrict__ y,
                                              const __bf16* __restrict__ vT,
                                              __bf16* __restrict__ ao) {
  __shared__ __align__(16) __bf16 Pp[4][16 * 36];   // per-wave P [q16][tok32+pad]
  int hd = blockIdx.x, b = blockIdx.y, qt = blockIdx.z;
  int t = threadIdx.x;
  int wv = t >> 6, lane = t & 63, l16 = lane & 15, quad = lane >> 4;
  int q0 = qt * 64 + wv * 16;

  const __bf16* base = y + (size_t)(b * HW_) * O3_ + hd * D_;
  const __bf16* vtg = vT + ((size_t)(b * C_) + hd * D_) * HW_;

  // Q B-frags (scale pre-folded in k_qkv): lane(n=l16, k-chunk=quad)
  bf16x8 qb[2];
#pragma unroll
  for (int dh = 0; dh < 2; dh++)
    qb[dh] = *(const bf16x8*)(base + (size_t)(q0 + l16) * O3_ +
                              dh * 32 + quad * 8);

  // per-lane fragment base pointers (MFMA A-frag layout, direct from global)
  const __bf16* kL = base + C_ + (size_t)l16 * O3_ + quad * 8;  // K[tok][d]
  const __bf16* vL = vtg + (size_t)l16 * HW_ + quad * 8;        // vT[d][tok]

  float l_run = 0.f;
  f32x4 o_acc[4];
#pragma unroll
  for (int dt = 0; dt < 4; dt++) o_acc[dt] = f32x4{0.f, 0.f, 0.f, 0.f};

  bf16x8 kaE[2][2], kaO[2][2], va[4];

  auto LK = [&](bf16x8 (&dst)[2][2], int s) {
#pragma unroll
    for (int tti = 0; tti < 2; tti++)
#pragma unroll
      for (int dh = 0; dh < 2; dh++)
        dst[tti][dh] = *(const bf16x8*)(kL + (size_t)(s * 32 + tti * 16) * O3_ +
                                        dh * 32);
  };
  auto LV = [&](int s) {
#pragma unroll
    for (int dt = 0; dt < 4; dt++)
      va[dt] = *(const bf16x8*)(vL + (size_t)(dt * 16) * HW_ + s * 32);
  };
  auto BODY = [&](bf16x8 (&ka)[2][2]) {
    f32x4 z = {0.f, 0.f, 0.f, 0.f};
    __builtin_amdgcn_s_setprio(1);
    f32x4 st0 = __builtin_amdgcn_mfma_f32_16x16x32_bf16(ka[0][0], qb[0], z, 0, 0, 0);
    st0 = __builtin_amdgcn_mfma_f32_16x16x32_bf16(ka[0][1], qb[1], st0, 0, 0, 0);
    f32x4 st1 = __builtin_amdgcn_mfma_f32_16x16x32_bf16(ka[1][0], qb[0], z, 0, 0, 0);
    st1 = __builtin_amdgcn_mfma_f32_16x16x32_bf16(ka[1][1], qb[1], st1, 0, 0, 0);
    __builtin_amdgcn_s_setprio(0);
    float rs = 0.f;
    bf16x4 p0, p1;
#pragma unroll
    for (int r = 0; r < 4; r++) {
      float e0 = __builtin_amdgcn_exp2f(st0[r]); rs += e0; p0[r] = (__bf16)e0;
      float e1 = __builtin_amdgcn_exp2f(st1[r]); rs += e1; p1[r] = (__bf16)e1;
    }
    l_run += rs;
    // P (C-layout: q=l16, tok=tti*16+quad*4+r) -> wave-local LDS
    *(bf16x4*)(&Pp[wv][l16 * 36 + quad * 4]) = p0;
    *(bf16x4*)(&Pp[wv][l16 * 36 + 16 + quad * 4]) = p1;
    asm volatile("s_waitcnt lgkmcnt(0)" ::: "memory");
    bf16x8 pb = *(const bf16x8*)(&Pp[wv][l16 * 36 + quad * 8]);
    __builtin_amdgcn_s_setprio(1);
#pragma unroll
    for (int dt = 0; dt < 4; dt++)
      o_acc[dt] = __builtin_amdgcn_mfma_f32_16x16x32_bf16(va[dt], pb,
                                                          o_acc[dt], 0, 0, 0);
    __builtin_amdgcn_s_setprio(0);
  };

  LK(kaE, 0);
  for (int s = 0; s < 32; s += 2) {
    LV(s);
    LK(kaO, s + 1);
    BODY(kaE);
    LV(s + 1);
    if (s + 2 < 32) LK(kaE, s + 2);
    BODY(kaO);
  }

  // softmax denominator: reduce over the 4 quads sharing q=l16
  l_run += __shfl_xor(l_run, 16, 64);
  l_run += __shfl_xor(l_run, 32, 64);
  float inv = 1.f / l_run;

  // epilogue: O^T C-layout (row=d=quad*4+r, col=q=l16) -> ao[b][q][c]
#pragma unroll
  for (int dt = 0; dt < 4; dt++) {
    bf16x4 pk;
#pragma unroll
    for (int r = 0; r < 4; r++) pk[r] = (__bf16)(o_acc[dt][r] * inv);
    int ch = hd * D_ + dt * 16 + quad * 4;
    *(bf16x4*)(ao + (size_t)(b * HW_ + q0 + l16) * C_ + ch) = pk;
  }
}

// ---------------------------------------------------------------------------
// Kernel 5: proj GEMM + bias + residual, out fp32 [b][o][hw]. (R2 version)
// ---------------------------------------------------------------------------
#define BK 64
__global__ __launch_bounds__(256) void k_proj(const __bf16* __restrict__ ao,
                                              const __bf16* __restrict__ w,
                                              const float* __restrict__ bias,
                                              const float* __restrict__ x,
                                              float* __restrict__ out) {
  __shared__ __align__(16) __bf16 As[2][128 * BK];   // w rows (o)
  __shared__ __align__(16) __bf16 Bs[2][64 * BK];    // ao rows (tok)
  int n0 = blockIdx.x * 64, m0 = blockIdx.y * 128;   // n = token, m = o
  int t = threadIdx.x;
  int lane = t & 63, l16 = lane & 15, quad = lane >> 4;
  int wv = t >> 6;
  int wm = (wv >> 1) * 64, wn = (wv & 1) * 32;

  int rsub = lane >> 3;
  int chunk = (lane & 7) ^ rsub;
  const __bf16* ag = w + (size_t)(m0 + wv * 32 + rsub) * C_ + chunk * 8;
  const __bf16* bg = ao + (size_t)(n0 + wv * 16 + rsub) * C_ + chunk * 8;
  int sw = l16 & 7;

  auto stage = [&](int k0, int bi) {        // exactly 6 VMEM ops per call
    __bf16* la = As[bi] + wv * 2048 + lane * 8;
    __bf16* lb = Bs[bi] + wv * 1024 + lane * 8;
#pragma unroll
    for (int s = 0; s < 4; s++)
      async_copy16(la + s * 512, ag + (size_t)(s * 8) * C_ + k0);
#pragma unroll
    for (int s = 0; s < 2; s++)
      async_copy16(lb + s * 512, bg + (size_t)(s * 8) * C_ + k0);
  };

  f32x4 acc[4][2];
#pragma unroll
  for (int i = 0; i < 4; i++)
#pragma unroll
    for (int j = 0; j < 2; j++) acc[i][j] = f32x4{0.f, 0.f, 0.f, 0.f};

  stage(0, 0);
  stage(1 * BK, 1);
  for (int kk = 0; kk < 8; kk++) {
    int bi = kk & 1;
    if (kk < 7)
      asm volatile("s_waitcnt vmcnt(6)\n\ts_barrier" ::: "memory");
    else
      asm volatile("s_waitcnt vmcnt(0)\n\ts_barrier" ::: "memory");
    const __bf16* as = As[bi];
    const __bf16* bs = Bs[bi];
    bf16x8 af[2][4], bf[2][2];
#pragma unroll
    for (int hh = 0; hh < 2; hh++) {
#pragma unroll
      for (int i = 0; i < 4; i++)
        af[hh][i] = *(const bf16x8*)(as + (wm + i * 16 + l16) * BK +
                                     ((hh * 4 + quad) ^ sw) * 8);
#pragma unroll
      for (int j = 0; j < 2; j++)
        bf[hh][j] = *(const bf16x8*)(bs + (wn + j * 16 + l16) * BK +
                                     ((hh * 4 + quad) ^ sw) * 8);
    }
    asm volatile("s_waitcnt lgkmcnt(0)\n\ts_barrier" ::: "memory");
    if (kk < 6) stage((kk + 2) * BK, bi);
    __builtin_amdgcn_s_setprio(1);
#pragma unroll
    for (int hh = 0; hh < 2; hh++)
#pragma unroll
      for (int i = 0; i < 4; i++)
#pragma unroll
        for (int j = 0; j < 2; j++)
          acc[i][j] = __builtin_amdgcn_mfma_f32_16x16x32_bf16(af[hh][i], bf[hh][j],
                                                              acc[i][j], 0, 0, 0);
    __builtin_amdgcn_s_setprio(0);
  }

  int bb = n0 >> 10;                        // batch uniform per block
#pragma unroll
  for (int i = 0; i < 4; i++)
#pragma unroll
    for (int r = 0; r < 4; r++) {
      int o = m0 + wm + i * 16 + quad * 4 + r;
      float bv = bias[o];
#pragma unroll
      for (int j = 0; j < 2; j++) {
        int n = n0 + wn + j * 16 + l16;
        int hw = n & 1023;
        size_t idx = ((size_t)(bb * C_ + o)) * HW_ + hw;
        out[idx] = acc[i][j][r] + bv + x[idx];
      }
    }
}

// ---------------------------------------------------------------------------
extern "C" void kernel_launch(void* const* d_in, const int* in_sizes, int n_in,
                              void* d_out, int out_size, void* d_ws, size_t ws_size,
                              hipStream_t stream) {
  const float* x      = (const float*)d_in[0];
  const float* gn_w   = (const float*)d_in[1];
  const float* gn_b   = (const float*)d_in[2];
  const float* qkv_w  = (const float*)d_in[3];
  const float* qkv_b  = (const float*)d_in[4];
  const float* proj_w = (const float*)d_in[5];
  const float* proj_b = (const float*)d_in[6];
  float* out = (float*)d_out;

  char* ws = (char*)d_ws;
  // layout: h 8MB | qwb 1.5MB | pwb 0.5MB | yq 24MB | ao 8MB | vT 8MB
  __bf16* h   = (__bf16*)(ws);
  __bf16* qwb = (__bf16*)(ws + 8388608);
  __bf16* pwb = (__bf16*)(ws + 8388608 + 1572864);
  __bf16* yq  = (__bf16*)(ws + 8388608 + 1572864 + 524288);
  __bf16* ao  = (__bf16*)(ws + 8388608 + 1572864 + 524288 + 25165824);
  __bf16* vT  = (__bf16*)(ws + 8388608 + 1572864 + 524288 + 25165824 + 8388608);

  k_gn  <<<B_ * G_ + 64, 1024, 0, stream>>>(x, gn_w, gn_b, h,
                                            qkv_w, proj_w, qwb, pwb);
  k_qkv <<<dim3(M_TOT / 128, O3_ / 128, 1), 256, 0, stream>>>(h, qwb, qkv_b, yq, vT);
  k_attn<<<dim3(HEADS_, B_, 16), 256, 0, stream>>>(yq, vT, ao);
  k_proj<<<dim3(M_TOT / 64, C_ / 128, 1), 256, 0, stream>>>(ao, pwb, proj_b, x, out);
  (void)in_sizes; (void)n_in; (void)out_size; (void)ws_size;
}

// Round 6
// 140.203 us; speedup vs baseline: 1.6270x; 1.6270x over previous
//
#include <hip/hip_runtime.h>
#include <math.h>

// Problem constants (B, C, H, W) = (8, 512, 32, 32)
#define B_    8
#define C_    512
#define HW_   1024
#define O3_   1536     // 3*C
#define HEADS_ 8
#define D_    64       // head dim
#define G_    32       // groups
#define CPG_  16       // channels per group
#define EPS_  1e-5f
#define M_TOT 8192     // B*HW

// softmax scale (1/sqrt(64)) folded with log2(e) so exp2 is exact softmax
#define QSCALE (0.125f * 1.44269504088896f)

typedef __bf16 bf16x8 __attribute__((ext_vector_type(8)));
typedef __bf16 bf16x4 __attribute__((ext_vector_type(4)));
typedef float  f32x4  __attribute__((ext_vector_type(4)));

// async global->LDS, 16B per lane (wave-uniform base + lane*16 layout)
__device__ __forceinline__ void async_copy16(void* lds, const void* g) {
  __builtin_amdgcn_global_load_lds(
      (const __attribute__((address_space(1))) unsigned int*)g,
      (__attribute__((address_space(3))) unsigned int*)lds, 16, 0, 0);
}

// ---------------------------------------------------------------------------
// Kernel 1: GroupNorm -> bf16 transposed to h[b][hw][c]. (R2 version)
// ---------------------------------------------------------------------------
__global__ __launch_bounds__(1024) void k_gn(const float* __restrict__ x,
                                             const float* __restrict__ gw,
                                             const float* __restrict__ gb,
                                             __bf16* __restrict__ h,
                                             const float* __restrict__ qw,
                                             const float* __restrict__ pw,
                                             __bf16* __restrict__ qwb,
                                             __bf16* __restrict__ pwb) {
  __shared__ float red[34];
  __shared__ __bf16 T[16 * 1032];          // transpose staging (pad: 8B rows)
  int tid = threadIdx.x;
  if (blockIdx.x >= B_ * G_) {             // conversion blocks, grid-stride x4
    int i0 = (blockIdx.x - B_ * G_) * 1024 + tid;
    for (int i = i0; i < O3_ * C_ / 4; i += 64 * 1024) {
      float4 v = ((const float4*)qw)[i];
      bf16x4 o = {(__bf16)v.x, (__bf16)v.y, (__bf16)v.z, (__bf16)v.w};
      ((bf16x4*)qwb)[i] = o;
    }
    for (int i = i0; i < C_ * C_ / 4; i += 64 * 1024) {
      float4 v = ((const float4*)pw)[i];
      bf16x4 o = {(__bf16)v.x, (__bf16)v.y, (__bf16)v.z, (__bf16)v.w};
      ((bf16x4*)pwb)[i] = o;
    }
    return;
  }
  int bg = blockIdx.x;
  int b = bg >> 5, g = bg & 31;
  const float4* xg4 = (const float4*)(x + ((size_t)(b * C_) + g * CPG_) * HW_);

  // pass 1: float4 loads, sum + sumsq (slab stays L2-hot for pass 2)
  float s = 0.f, ss = 0.f;
  for (int i = tid; i < CPG_ * HW_ / 4; i += 1024) {
    float4 v = xg4[i];
    s += v.x + v.y + v.z + v.w;
    ss += v.x * v.x + v.y * v.y + v.z * v.z + v.w * v.w;
  }
  for (int off = 32; off > 0; off >>= 1) {
    s  += __shfl_down(s, off, 64);
    ss += __shfl_down(ss, off, 64);
  }
  int wv = tid >> 6;
  if ((tid & 63) == 0) { red[wv] = s; red[16 + wv] = ss; }
  __syncthreads();
  if (tid == 0) {
    float S = 0.f, SS = 0.f;
#pragma unroll
    for (int i = 0; i < 16; i++) { S += red[i]; SS += red[16 + i]; }
    float mean = S / (float)(CPG_ * HW_);
    float var  = SS / (float)(CPG_ * HW_) - mean * mean;
    red[32] = mean;
    red[33] = rsqrtf(var + EPS_);
  }
  __syncthreads();
  float mean = red[32], rstd = red[33];

  // pass 2: re-read slab (L2-hot), normalize, packed bf16x4 writes into T
  for (int i = tid; i < CPG_ * HW_ / 4; i += 1024) {
    int c = i >> 8;
    int hw4 = (i & 255) * 4;
    float ga = gw[g * CPG_ + c], be = gb[g * CPG_ + c];
    float4 v = xg4[i];
    bf16x4 pk;
    pk[0] = (__bf16)((v.x - mean) * rstd * ga + be);
    pk[1] = (__bf16)((v.y - mean) * rstd * ga + be);
    pk[2] = (__bf16)((v.z - mean) * rstd * ga + be);
    pk[3] = (__bf16)((v.w - mean) * rstd * ga + be);
    *(bf16x4*)(&T[c * 1032 + hw4]) = pk;
  }
  __syncthreads();

  // pass 3: gather 8 channels per thread, packed 16B global stores
  __bf16* hb = h + (size_t)b * HW_ * C_ + g * CPG_;
  for (int j = tid; j < 2 * HW_; j += 1024) {
    int hw = j >> 1, c8 = (j & 1) * 8;
    bf16x8 v;
#pragma unroll
    for (int jj = 0; jj < 8; jj++) v[jj] = T[(c8 + jj) * 1032 + hw];
    *(bf16x8*)(hb + (size_t)hw * C_ + c8) = v;
  }
}

// ---------------------------------------------------------------------------
// Kernel 3: QKV GEMM — R2 best (BK=32, 128x128 tile, 3 blocks/CU, depth-2
// prefetch with counted vmcnt(4)).
// ---------------------------------------------------------------------------
#define BKQ 32
__global__ __launch_bounds__(256, 3) void k_qkv(const __bf16* __restrict__ h,
                                                const __bf16* __restrict__ w,
                                                const float* __restrict__ bias,
                                                __bf16* __restrict__ y,
                                                __bf16* __restrict__ vT) {
  __shared__ __align__(16) __bf16 As[2][128 * BKQ];
  __shared__ __align__(16) __bf16 Bs[2][128 * BKQ];
  int m0 = blockIdx.x * 128, n0 = blockIdx.y * 128;
  int t = threadIdx.x;
  int lane = t & 63, l16 = lane & 15, quad = lane >> 4;
  int wv = t >> 6;
  int wm = (wv >> 1) * 64, wn = (wv & 1) * 64;

  int rsub = lane >> 2;                     // row (0..15) within the 16-row copy
  int chunk = (lane & 3) ^ (rsub & 3);      // XOR chunk swizzle (4 chunks/row)
  const __bf16* ag = h + (size_t)(m0 + wv * 32 + rsub) * C_ + chunk * 8;
  const __bf16* bg = w + (size_t)(n0 + wv * 32 + rsub) * C_ + chunk * 8;
  int sw = l16 & 3;                         // read-side row&3

  auto stage = [&](int k0, int bi) {        // exactly 4 VMEM ops per call
    __bf16* la = As[bi] + wv * 1024 + lane * 8;
    __bf16* lb = Bs[bi] + wv * 1024 + lane * 8;
#pragma unroll
    for (int s = 0; s < 2; s++) {
      async_copy16(la + s * 512, ag + (size_t)(s * 16) * C_ + k0);
      async_copy16(lb + s * 512, bg + (size_t)(s * 16) * C_ + k0);
    }
  };

  f32x4 acc[4][4];
#pragma unroll
  for (int i = 0; i < 4; i++)
#pragma unroll
    for (int j = 0; j < 4; j++) acc[i][j] = f32x4{0.f, 0.f, 0.f, 0.f};

  stage(0, 0);
  stage(1 * BKQ, 1);
  for (int kk = 0; kk < 16; kk++) {
    int bi = kk & 1;
    // wait only the oldest 4 loads (buffer bi); 4 newer stay in flight
    if (kk < 15)
      asm volatile("s_waitcnt vmcnt(4)\n\ts_barrier" ::: "memory");
    else
      asm volatile("s_waitcnt vmcnt(0)\n\ts_barrier" ::: "memory");
    const __bf16* as = As[bi];
    const __bf16* bs = Bs[bi];
    bf16x8 af[4], bf[4];
#pragma unroll
    for (int i = 0; i < 4; i++) {
      af[i] = *(const bf16x8*)(as + (wm + i * 16 + l16) * BKQ + (quad ^ sw) * 8);
      bf[i] = *(const bf16x8*)(bs + (wn + i * 16 + l16) * BKQ + (quad ^ sw) * 8);
    }
    // all waves done reading bi -> safe to overwrite it with k+2 tile
    asm volatile("s_waitcnt lgkmcnt(0)\n\ts_barrier" ::: "memory");
    if (kk < 14) stage((kk + 2) * BKQ, bi);
    __builtin_amdgcn_s_setprio(1);
#pragma unroll
    for (int i = 0; i < 4; i++)
#pragma unroll
      for (int j = 0; j < 4; j++)
        acc[i][j] = __builtin_amdgcn_mfma_f32_16x16x32_bf16(af[i], bf[j],
                                                            acc[i][j], 0, 0, 0);
    __builtin_amdgcn_s_setprio(0);
  }

  if (n0 >= 2 * C_) {
    // V region -> vT[b][c][tok]; tok = m, c = n - 1024. b uniform per block.
    int bb = m0 >> 10;
    int tokBase = (m0 & 1023) + wm + quad * 4;
#pragma unroll
    for (int j = 0; j < 4; j++) {
      int n = n0 + wn + j * 16 + l16;
      int c = n - 2 * C_;
      float bv = bias[n];
      __bf16* vrow = vT + ((size_t)(bb * C_) + c) * HW_;
#pragma unroll
      for (int i = 0; i < 4; i++) {
        bf16x4 pk;
#pragma unroll
        for (int r = 0; r < 4; r++) pk[r] = (__bf16)(acc[i][j][r] + bv);
        *(bf16x4*)(vrow + tokBase + i * 16) = pk;
      }
    }
  } else {
    float sc = (n0 < C_) ? QSCALE : 1.0f;  // block-uniform (region edges %128)
#pragma unroll
    for (int j = 0; j < 4; j++) {
      int n = n0 + wn + j * 16 + l16;
      float bv = bias[n];
#pragma unroll
      for (int i = 0; i < 4; i++)
#pragma unroll
        for (int r = 0; r < 4; r++) {
          int m = m0 + wm + i * 16 + quad * 4 + r;
          y[(size_t)m * O3_ + n] = (__bf16)((acc[i][j][r] + bv) * sc);
        }
    }
  }
}

// ---------------------------------------------------------------------------
// Kernel 4: flash attention — R2 staged structure + T15 stagger: QK of slice
// kh+1 is issued BEFORE the softmax-finish+PV of slice kh, using two static
// score states (sE/sO). The exp/pack VALU of slice kh then overlaps the
// matrix pipe's QK of kh+1 (and PV of kh overlaps the next exp). 3 of 4
// slices per 128-tok step are overlapped; Pp single-slot stays correct via
// within-wave LDS ordering. Staging/dbuf/barrier schedule identical to R2.
// ---------------------------------------------------------------------------
__global__ __launch_bounds__(256) void k_attn(const __bf16* __restrict__ y,
                                              const __bf16* __restrict__ vT,
                                              __bf16* __restrict__ ao) {
  __shared__ __align__(16) __bf16 Ks[2][128 * 64];   // [tok][d], chunk-swizzled
  __shared__ __align__(16) __bf16 Vt[2][64 * 128];   // [d][tok], chunk-swizzled
  __shared__ __align__(16) __bf16 Pp[4][32 * 36];    // per-wave P slice [q][tok32]
  int hd = blockIdx.x, b = blockIdx.y, qt = blockIdx.z;
  int t = threadIdx.x;
  int wv = t >> 6, lane = t & 63, l16 = lane & 15, quad = lane >> 4;
  int q0 = qt * 128 + wv * 32;

  const __bf16* base = y + (size_t)(b * HW_) * O3_ + hd * D_;
  const __bf16* kg = base + C_;
  const __bf16* vtg = vT + ((size_t)(b * C_) + hd * D_) * HW_;

  // Q B-frags [qg][dh] (scale pre-folded in k_qkv)
  bf16x8 qb[2][2];
#pragma unroll
  for (int qg = 0; qg < 2; qg++)
#pragma unroll
    for (int dh = 0; dh < 2; dh++)
      qb[qg][dh] = *(const bf16x8*)(base + (size_t)(q0 + qg * 16 + l16) * O3_ +
                                    dh * 32 + quad * 8);

  int kRowSub = lane >> 3;
  int kChunk = (lane & 7) ^ (kRowSub & 7);

  auto stage = [&](int kt, int bi) {
#pragma unroll
    for (int s = 0; s < 4; s++) {
      int row = wv * 32 + s * 8 + kRowSub;
      async_copy16(&Ks[bi][(wv * 32 + s * 8) * 64 + lane * 8],
                   kg + (size_t)(kt + row) * O3_ + kChunk * 8);
    }
#pragma unroll
    for (int s = 0; s < 4; s++) {
      int row = wv * 16 + s * 4 + (lane >> 4);
      int c2 = (lane & 15) ^ (row & 15);
      async_copy16(&Vt[bi][(wv * 16 + s * 4) * 128 + lane * 8],
                   vtg + (size_t)row * HW_ + kt + c2 * 8);
    }
  };

  float l_run[2] = {0.f, 0.f};
  f32x4 o_acc[4][2];
#pragma unroll
  for (int dt = 0; dt < 4; dt++)
#pragma unroll
    for (int qg = 0; qg < 2; qg++) o_acc[dt][qg] = f32x4{0.f, 0.f, 0.f, 0.f};

  // two static score states (T15; rule #20: no runtime indexing)
  f32x4 sE[2][2], sO[2][2];

  // QK for one 32-tok slice kh into st
  auto QK = [&](f32x4 (&st)[2][2], const __bf16* ks, int kh) {
    __builtin_amdgcn_s_setprio(1);
#pragma unroll
    for (int tti = 0; tti < 2; tti++) {
      int row = (kh * 2 + tti) * 16 + l16;
      bf16x8 ka0 = *(const bf16x8*)(&ks[row * 64 + ((quad) ^ (l16 & 7)) * 8]);
      bf16x8 ka1 = *(const bf16x8*)(&ks[row * 64 + ((4 + quad) ^ (l16 & 7)) * 8]);
      f32x4 z = {0.f, 0.f, 0.f, 0.f};
      st[tti][0] = __builtin_amdgcn_mfma_f32_16x16x32_bf16(ka0, qb[0][0], z, 0, 0, 0);
      st[tti][0] = __builtin_amdgcn_mfma_f32_16x16x32_bf16(ka1, qb[0][1], st[tti][0], 0, 0, 0);
      st[tti][1] = __builtin_amdgcn_mfma_f32_16x16x32_bf16(ka0, qb[1][0], z, 0, 0, 0);
      st[tti][1] = __builtin_amdgcn_mfma_f32_16x16x32_bf16(ka1, qb[1][1], st[tti][1], 0, 0, 0);
    }
    __builtin_amdgcn_s_setprio(0);
  };

  // softmax-finish + PV for slice kh (consumes st)
  auto FIN = [&](f32x4 (&st)[2][2], const __bf16* vs, int kh) {
#pragma unroll
    for (int qg = 0; qg < 2; qg++) {
      float rs = 0.f;
#pragma unroll
      for (int tti = 0; tti < 2; tti++)
#pragma unroll
        for (int r = 0; r < 4; r++) {
          float e = __builtin_amdgcn_exp2f(st[tti][qg][r]);
          st[tti][qg][r] = e;
          rs += e;
        }
      l_run[qg] += rs;    // cross-lane reduce deferred to epilogue
    }
#pragma unroll
    for (int qg = 0; qg < 2; qg++)
#pragma unroll
      for (int tti = 0; tti < 2; tti++) {
        bf16x4 pk;
#pragma unroll
        for (int r = 0; r < 4; r++) pk[r] = (__bf16)st[tti][qg][r];
        *(bf16x4*)(&Pp[wv][(qg * 16 + l16) * 36 + tti * 16 + quad * 4]) = pk;
      }
    asm volatile("s_waitcnt lgkmcnt(0)" ::: "memory");
    bf16x8 pb0 = *(const bf16x8*)(&Pp[wv][l16 * 36 + quad * 8]);
    bf16x8 pb1 = *(const bf16x8*)(&Pp[wv][(16 + l16) * 36 + quad * 8]);
    __builtin_amdgcn_s_setprio(1);
#pragma unroll
    for (int dt = 0; dt < 4; dt++) {
      int vpos = ((kh * 4 + quad) ^ l16) * 8;   // row&15 == l16
      bf16x8 va = *(const bf16x8*)(&vs[(dt * 16 + l16) * 128 + vpos]);
      o_acc[dt][0] = __builtin_amdgcn_mfma_f32_16x16x32_bf16(va, pb0, o_acc[dt][0], 0, 0, 0);
      o_acc[dt][1] = __builtin_amdgcn_mfma_f32_16x16x32_bf16(va, pb1, o_acc[dt][1], 0, 0, 0);
    }
    __builtin_amdgcn_s_setprio(0);
  };

  stage(0, 0);

  for (int step = 0; step < 8; step++) {
    int bi = step & 1;
    asm volatile("s_waitcnt vmcnt(0)\n\ts_barrier" ::: "memory");
    if (step < 7) stage((step + 1) * 128, bi ^ 1);

    const __bf16* ks = Ks[bi];
    const __bf16* vs = Vt[bi];
    // T15 staggered pipeline over the 4 32-tok slices:
    QK(sE, ks, 0);
    QK(sO, ks, 1); FIN(sE, vs, 0);
    QK(sE, ks, 2); FIN(sO, vs, 1);
    QK(sO, ks, 3); FIN(sE, vs, 2);
    FIN(sO, vs, 3);
  }

  // deferred softmax denominator: reduce over the 4 quads sharing q=l16
#pragma unroll
  for (int qg = 0; qg < 2; qg++) {
    l_run[qg] += __shfl_xor(l_run[qg], 16, 64);
    l_run[qg] += __shfl_xor(l_run[qg], 32, 64);
  }
  float inv0 = 1.f / l_run[0], inv1 = 1.f / l_run[1];

  // epilogue: O^T C-layout (row=d=quad*4+r, col=q=l16) -> ao[b][q][c], packed
#pragma unroll
  for (int dt = 0; dt < 4; dt++) {
    bf16x4 p0, p1;
#pragma unroll
    for (int r = 0; r < 4; r++) {
      p0[r] = (__bf16)(o_acc[dt][0][r] * inv0);
      p1[r] = (__bf16)(o_acc[dt][1][r] * inv1);
    }
    int ch = hd * D_ + dt * 16 + quad * 4;
    *(bf16x4*)(ao + (size_t)(b * HW_ + q0 + l16) * C_ + ch) = p0;
    *(bf16x4*)(ao + (size_t)(b * HW_ + q0 + 16 + l16) * C_ + ch) = p1;
  }
}

// ---------------------------------------------------------------------------
// Kernel 5: proj GEMM + bias + residual, out fp32 [b][o][hw]. (R2 version)
// ---------------------------------------------------------------------------
#define BK 64
__global__ __launch_bounds__(256) void k_proj(const __bf16* __restrict__ ao,
                                              const __bf16* __restrict__ w,
                                              const float* __restrict__ bias,
                                              const float* __restrict__ x,
                                              float* __restrict__ out) {
  __shared__ __align__(16) __bf16 As[2][128 * BK];   // w rows (o)
  __shared__ __align__(16) __bf16 Bs[2][64 * BK];    // ao rows (tok)
  int n0 = blockIdx.x * 64, m0 = blockIdx.y * 128;   // n = token, m = o
  int t = threadIdx.x;
  int lane = t & 63, l16 = lane & 15, quad = lane >> 4;
  int wv = t >> 6;
  int wm = (wv >> 1) * 64, wn = (wv & 1) * 32;

  int rsub = lane >> 3;
  int chunk = (lane & 7) ^ rsub;
  const __bf16* ag = w + (size_t)(m0 + wv * 32 + rsub) * C_ + chunk * 8;
  const __bf16* bg = ao + (size_t)(n0 + wv * 16 + rsub) * C_ + chunk * 8;
  int sw = l16 & 7;

  auto stage = [&](int k0, int bi) {        // exactly 6 VMEM ops per call
    __bf16* la = As[bi] + wv * 2048 + lane * 8;
    __bf16* lb = Bs[bi] + wv * 1024 + lane * 8;
#pragma unroll
    for (int s = 0; s < 4; s++)
      async_copy16(la + s * 512, ag + (size_t)(s * 8) * C_ + k0);
#pragma unroll
    for (int s = 0; s < 2; s++)
      async_copy16(lb + s * 512, bg + (size_t)(s * 8) * C_ + k0);
  };

  f32x4 acc[4][2];
#pragma unroll
  for (int i = 0; i < 4; i++)
#pragma unroll
    for (int j = 0; j < 2; j++) acc[i][j] = f32x4{0.f, 0.f, 0.f, 0.f};

  stage(0, 0);
  stage(1 * BK, 1);
  for (int kk = 0; kk < 8; kk++) {
    int bi = kk & 1;
    if (kk < 7)
      asm volatile("s_waitcnt vmcnt(6)\n\ts_barrier" ::: "memory");
    else
      asm volatile("s_waitcnt vmcnt(0)\n\ts_barrier" ::: "memory");
    const __bf16* as = As[bi];
    const __bf16* bs = Bs[bi];
    bf16x8 af[2][4], bf[2][2];
#pragma unroll
    for (int hh = 0; hh < 2; hh++) {
#pragma unroll
      for (int i = 0; i < 4; i++)
        af[hh][i] = *(const bf16x8*)(as + (wm + i * 16 + l16) * BK +
                                     ((hh * 4 + quad) ^ sw) * 8);
#pragma unroll
      for (int j = 0; j < 2; j++)
        bf[hh][j] = *(const bf16x8*)(bs + (wn + j * 16 + l16) * BK +
                                     ((hh * 4 + quad) ^ sw) * 8);
    }
    asm volatile("s_waitcnt lgkmcnt(0)\n\ts_barrier" ::: "memory");
    if (kk < 6) stage((kk + 2) * BK, bi);
    __builtin_amdgcn_s_setprio(1);
#pragma unroll
    for (int hh = 0; hh < 2; hh++)
#pragma unroll
      for (int i = 0; i < 4; i++)
#pragma unroll
        for (int j = 0; j < 2; j++)
          acc[i][j] = __builtin_amdgcn_mfma_f32_16x16x32_bf16(af[hh][i], bf[hh][j],
                                                              acc[i][j], 0, 0, 0);
    __builtin_amdgcn_s_setprio(0);
  }

  int bb = n0 >> 10;                        // batch uniform per block
#pragma unroll
  for (int i = 0; i < 4; i++)
#pragma unroll
    for (int r = 0; r < 4; r++) {
      int o = m0 + wm + i * 16 + quad * 4 + r;
      float bv = bias[o];
#pragma unroll
      for (int j = 0; j < 2; j++) {
        int n = n0 + wn + j * 16 + l16;
        int hw = n & 1023;
        size_t idx = ((size_t)(bb * C_ + o)) * HW_ + hw;
        out[idx] = acc[i][j][r] + bv + x[idx];
      }
    }
}

// ---------------------------------------------------------------------------
extern "C" void kernel_launch(void* const* d_in, const int* in_sizes, int n_in,
                              void* d_out, int out_size, void* d_ws, size_t ws_size,
                              hipStream_t stream) {
  const float* x      = (const float*)d_in[0];
  const float* gn_w   = (const float*)d_in[1];
  const float* gn_b   = (const float*)d_in[2];
  const float* qkv_w  = (const float*)d_in[3];
  const float* qkv_b  = (const float*)d_in[4];
  const float* proj_w = (const float*)d_in[5];
  const float* proj_b = (const float*)d_in[6];
  float* out = (float*)d_out;

  char* ws = (char*)d_ws;
  // layout: h 8MB | qwb 1.5MB | pwb 0.5MB | yq 24MB | ao 8MB | vT 8MB
  __bf16* h   = (__bf16*)(ws);
  __bf16* qwb = (__bf16*)(ws + 8388608);
  __bf16* pwb = (__bf16*)(ws + 8388608 + 1572864);
  __bf16* yq  = (__bf16*)(ws + 8388608 + 1572864 + 524288);
  __bf16* ao  = (__bf16*)(ws + 8388608 + 1572864 + 524288 + 25165824);
  __bf16* vT  = (__bf16*)(ws + 8388608 + 1572864 + 524288 + 25165824 + 8388608);

  k_gn  <<<B_ * G_ + 64, 1024, 0, stream>>>(x, gn_w, gn_b, h,
                                            qkv_w, proj_w, qwb, pwb);
  k_qkv <<<dim3(M_TOT / 128, O3_ / 128, 1), 256, 0, stream>>>(h, qwb, qkv_b, yq, vT);
  k_attn<<<dim3(HEADS_, B_, 8), 256, 0, stream>>>(yq, vT, ao);
  k_proj<<<dim3(M_TOT / 64, C_ / 128, 1), 256, 0, stream>>>(ao, pwb, proj_b, x, out);
  (void)in_sizes; (void)n_in; (void)out_size; (void)ws_size;
}